// Round 20
// baseline (75.069 us; speedup 1.0000x reference)
//
#include <hip/hip_runtime.h>
#include <hip/hip_bf16.h>

// Problem constants
#define N 1024
#define NF 27
#define EF 17
#define H 128
#define HEADS 4
#define HD 32

typedef __attribute__((ext_vector_type(8))) short bf16x8;
typedef __attribute__((ext_vector_type(16))) float f32x16;

__device__ __forceinline__ short f2bf(float x) {
  return __builtin_bit_cast(short, __float2bfloat16(x));
}
__device__ __forceinline__ unsigned pk2bf(float a, float b) {
  const unsigned lo = (unsigned short)f2bf(a);
  const unsigned hi = (unsigned short)f2bf(b);
  return lo | (hi << 16);
}

// =================== FRONT: prep + encoder + projections (fused, 2 rows/block) ===================
__global__ __launch_bounds__(256) void k_front(
    const float* __restrict__ nf,
    const float* __restrict__ ew1, const float* __restrict__ eb1,
    const float* __restrict__ ew2, const float* __restrict__ eb2,
    const float* __restrict__ ipw, const float* __restrict__ ipb,
    const float* __restrict__ pw1, const float* __restrict__ pb1,
    const float* __restrict__ cw1, const float* __restrict__ pw2,
    float* __restrict__ q, float* __restrict__ kkT,
    float* __restrict__ sa_pb, float* __restrict__ sb_ps,
    float* __restrict__ sa_c, float* __restrict__ sb_cT,
    unsigned short* __restrict__ w2f)
{
  const int t = threadIdx.x;
  if (blockIdx.x == 512) {
    if (t < 64) {
      const int lane = t, col = lane & 31, hsel = lane >> 5;
      for (int kc = 0; kc < 8; ++kc)
        for (int e = 0; e < 8; ++e) {
          const int k = kc * 16 + hsel * 8 + e;
          w2f[(kc * 64 + lane) * 8 + e] =
              (unsigned short)((col < EF) ? (unsigned short)f2bf(pw2[k * EF + col]) : 0);
        }
    }
    return;
  }

  __shared__ float s_nf[2 * NF];
  __shared__ float s_h1[2][H];
  __shared__ float s_e[2][H];
  const int i0 = blockIdx.x * 2;
  if (t < 2 * NF) s_nf[t] = nf[i0 * NF + t];
  __syncthreads();

  {
    const int ti = t >> 7, c = t & 127;
    float h = eb1[c];
    #pragma unroll
    for (int f = 0; f < NF; ++f) h = fmaf(s_nf[ti * NF + f], ew1[f * H + c], h);
    s_h1[ti][c] = fmaxf(h, 0.f);
  }
  __syncthreads();
  {
    const int ti = t >> 7, c = t & 127;
    float e = eb2[c];
    #pragma unroll 8
    for (int k = 0; k < H; ++k) e = fmaf(s_h1[ti][k], ew2[k * H + c], e);
    s_e[ti][c] = e;
  }
  __syncthreads();

  for (int c = t; c < 640; c += 256) {
    float a0, a1;
    if (c < 256) {
      a0 = ipb[c]; a1 = a0;
      const float* wcol = ipw + c;
      #pragma unroll 8
      for (int k = 0; k < H; ++k) {
        const float w = wcol[k * 384];
        a0 = fmaf(s_e[0][k], w, a0); a1 = fmaf(s_e[1][k], w, a1);
      }
      if (c < 128) { q[i0 * H + c] = a0; q[(i0 + 1) * H + c] = a1; }
      else { kkT[(c - 128) * N + i0] = a0; kkT[(c - 128) * N + i0 + 1] = a1; }
    } else if (c < 512) {
      const int cc = (c < 384) ? (c - 256) : (c - 384);
      const float* wcol = (c < 384) ? (pw1 + cc) : (pw1 + 128 * H + cc);
      a0 = 0.f; a1 = 0.f;
      #pragma unroll 8
      for (int k = 0; k < H; ++k) {
        const float w = wcol[k * H];
        a0 = fmaf(s_e[0][k], w, a0); a1 = fmaf(s_e[1][k], w, a1);
      }
      if (c < 384) {
        const float b = pb1[cc];
        sa_pb[i0 * H + cc] = a0 + b;
        sa_pb[(i0 + 1) * H + cc] = a1 + b;
      } else {
        const int J = i0 >> 5, jl = i0 & 31;
        const int kc = cc >> 4, hs = (cc >> 3) & 1, hf = (cc >> 2) & 1, pos = cc & 3;
        const int base = ((J * 32 + kc * 4 + hs * 2 + hf) * 32) * 4 + pos;
        sb_ps[base + jl * 4] = a0;
        sb_ps[base + (jl + 1) * 4] = a1;
      }
    } else {
      const int cc = (c < 576) ? (c - 512) : (c - 576);
      const float* wcol = (c < 576) ? (cw1 + cc) : (cw1 + 128 * 64 + cc);
      a0 = 0.f; a1 = 0.f;
      #pragma unroll 8
      for (int k = 0; k < H; ++k) {
        const float w = wcol[k * 64];
        a0 = fmaf(s_e[0][k], w, a0); a1 = fmaf(s_e[1][k], w, a1);
      }
      if (c < 576) { sa_c[i0 * 64 + cc] = a0; sa_c[(i0 + 1) * 64 + cc] = a1; }
      else { sb_cT[cc * N + i0] = a0; sb_cT[cc * N + i0 + 1] = a1; }
    }
  }
}

// =================== MAIN: pair (0..4095) || attn (4096..4607) || cls (4608..5119) ===================
#define PAIR_BLOCKS 4096
#define ATTN_BLOCKS 512
#define CLS_BLOCKS  512

__global__ __launch_bounds__(256) void k_main(
    const float* __restrict__ sa_pb, const float* __restrict__ sb_ps,
    const unsigned short* __restrict__ w2f, const float* __restrict__ pb2,
    const float* __restrict__ q, const float* __restrict__ kkT,
    const float* __restrict__ sa_c, const float* __restrict__ sb_cT,
    const float* __restrict__ cb1, const float* __restrict__ cw2, const float* __restrict__ cb2,
    float* __restrict__ out0, float* __restrict__ out1, float* __restrict__ out2)
{
  __shared__ float4 s_buf[1024];   // 16 KB union across paths
  const int t = threadIdx.x;
  const int b = blockIdx.x;

  if (b < PAIR_BLOCKS) {
    // ---- pair path: sb in LDS, ap straight from global (uniform half-wave addr, L1-hot) ----
    float4* s_sb = s_buf;                       // 1024 float4

    const int lane = t & 63, wid = t >> 6;
    const int It = b >> 5;     // 0..127 (8 i's each)
    const int J  = b & 31;     // j-tile (32 j's)
    const int i0 = It * 8;
    const int col = lane & 31, hsel = lane >> 5;

    const float4* g_sb = ((const float4*)sb_ps) + J * 1024;
    #pragma unroll
    for (int c = t; c < 1024; c += 256) s_sb[c] = g_sb[c];

    const bf16x8* w2f8 = (const bf16x8*)w2f;
    bf16x8 bfrag[8];
    #pragma unroll
    for (int kc = 0; kc < 8; ++kc) bfrag[kc] = w2f8[kc * 64 + lane];
    const float pb2c = (col < EF) ? pb2[col] : 0.f;
    __syncthreads();

    const int ia = wid * 2, ib = ia + 1;
    const float* gapA = sa_pb + (i0 + ia) * H + hsel * 8;   // per-half-wave uniform base
    const float* gapB = sa_pb + (i0 + ib) * H + hsel * 8;
    f32x16 accA, accB;
    #pragma unroll
    for (int r = 0; r < 16; ++r) { accA[r] = pb2c; accB[r] = pb2c; }

    #pragma unroll
    for (int kc = 0; kc < 8; ++kc) {
      const int cl = (kc * 4 + hsel * 2) * 32 + col;
      const float4 v0 = s_sb[cl];
      const float4 v1 = s_sb[cl + 32];
      const float4 a0 = *(const float4*)(gapA + kc * 16);
      const float4 a1 = *(const float4*)(gapA + kc * 16 + 4);
      const float4 b0 = *(const float4*)(gapB + kc * 16);
      const float4 b1 = *(const float4*)(gapB + kc * 16 + 4);
      union { bf16x8 v8; unsigned u[4]; } uA, uB;
      uA.u[0] = pk2bf(fmaxf(a0.x + v0.x, 0.f), fmaxf(a0.y + v0.y, 0.f));
      uA.u[1] = pk2bf(fmaxf(a0.z + v0.z, 0.f), fmaxf(a0.w + v0.w, 0.f));
      uA.u[2] = pk2bf(fmaxf(a1.x + v1.x, 0.f), fmaxf(a1.y + v1.y, 0.f));
      uA.u[3] = pk2bf(fmaxf(a1.z + v1.z, 0.f), fmaxf(a1.w + v1.w, 0.f));
      uB.u[0] = pk2bf(fmaxf(b0.x + v0.x, 0.f), fmaxf(b0.y + v0.y, 0.f));
      uB.u[1] = pk2bf(fmaxf(b0.z + v0.z, 0.f), fmaxf(b0.w + v0.w, 0.f));
      uB.u[2] = pk2bf(fmaxf(b1.x + v1.x, 0.f), fmaxf(b1.y + v1.y, 0.f));
      uB.u[3] = pk2bf(fmaxf(b1.z + v1.z, 0.f), fmaxf(b1.w + v1.w, 0.f));
      accA = __builtin_amdgcn_mfma_f32_32x32x16_bf16(uA.v8, bfrag[kc], accA, 0, 0, 0);
      accB = __builtin_amdgcn_mfma_f32_32x32x16_bf16(uB.v8, bfrag[kc], accB, 0, 0, 0);
    }

    if (col < EF) {
      const int jbase = J * 32 + 4 * hsel;
      float* oA = out2 + ((size_t)(i0 + ia) * N + jbase) * EF + col;
      float* oB = out2 + ((size_t)(i0 + ib) * N + jbase) * EF + col;
      #pragma unroll
      for (int r = 0; r < 16; ++r) {
        const int off = ((r & 3) + 8 * (r >> 2)) * EF;
        oA[off] = accA[r];
        oB[off] = accB[r];
      }
    }
    return;
  }

  if (b < PAIR_BLOCKS + ATTN_BLOCKS) {
    // ---------------- attention path ----------------
    float (*s_q)[H] = (float(*)[H])s_buf;
    float (*s_redm)[4] = (float(*)[4])((float*)s_buf + 2 * H);
    float (*s_reds)[4] = (float(*)[4])((float*)s_buf + 2 * H + 32);

    const int i0 = (b - PAIR_BLOCKS) * 2;
    const int w = t >> 6, lane = t & 63;
    s_q[t >> 7][t & 127] = q[(i0 + (t >> 7)) * H + (t & 127)];
    __syncthreads();

    const float scale = 0.17677669529663687f;  // 1/sqrt(32)
    const float4* kT4 = (const float4*)kkT;
    float4 sc[2][4];

    #pragma unroll
    for (int h = 0; h < HEADS; ++h) {
      float4 a0 = {0.f, 0.f, 0.f, 0.f}, a1 = {0.f, 0.f, 0.f, 0.f};
      #pragma unroll 8
      for (int d = 0; d < HD; ++d) {
        const float4 kv = kT4[(h * HD + d) * 256 + t];
        const float q0 = s_q[0][h * HD + d], q1 = s_q[1][h * HD + d];
        a0.x = fmaf(q0, kv.x, a0.x); a0.y = fmaf(q0, kv.y, a0.y);
        a0.z = fmaf(q0, kv.z, a0.z); a0.w = fmaf(q0, kv.w, a0.w);
        a1.x = fmaf(q1, kv.x, a1.x); a1.y = fmaf(q1, kv.y, a1.y);
        a1.z = fmaf(q1, kv.z, a1.z); a1.w = fmaf(q1, kv.w, a1.w);
      }
      sc[0][h].x = a0.x * scale; sc[0][h].y = a0.y * scale;
      sc[0][h].z = a0.z * scale; sc[0][h].w = a0.w * scale;
      sc[1][h].x = a1.x * scale; sc[1][h].y = a1.y * scale;
      sc[1][h].z = a1.z * scale; sc[1][h].w = a1.w * scale;
    }

    float m[2][4];
    #pragma unroll
    for (int ti = 0; ti < 2; ++ti)
      #pragma unroll
      for (int h = 0; h < HEADS; ++h) {
        float mm = fmaxf(fmaxf(sc[ti][h].x, sc[ti][h].y), fmaxf(sc[ti][h].z, sc[ti][h].w));
        for (int off = 32; off; off >>= 1) mm = fmaxf(mm, __shfl_xor(mm, off));
        if (lane == 0) s_redm[ti * 4 + h][w] = mm;
      }
    __syncthreads();
    #pragma unroll
    for (int ti = 0; ti < 2; ++ti)
      #pragma unroll
      for (int h = 0; h < HEADS; ++h) {
        const int idx = ti * 4 + h;
        m[ti][h] = fmaxf(fmaxf(s_redm[idx][0], s_redm[idx][1]),
                         fmaxf(s_redm[idx][2], s_redm[idx][3]));
      }

    float inv[2][4];
    #pragma unroll
    for (int ti = 0; ti < 2; ++ti)
      #pragma unroll
      for (int h = 0; h < HEADS; ++h) {
        sc[ti][h].x = __expf(sc[ti][h].x - m[ti][h]);
        sc[ti][h].y = __expf(sc[ti][h].y - m[ti][h]);
        sc[ti][h].z = __expf(sc[ti][h].z - m[ti][h]);
        sc[ti][h].w = __expf(sc[ti][h].w - m[ti][h]);
        float s = sc[ti][h].x + sc[ti][h].y + sc[ti][h].z + sc[ti][h].w;
        for (int off = 32; off; off >>= 1) s += __shfl_xor(s, off);
        if (lane == 0) s_reds[ti * 4 + h][w] = s;
      }
    __syncthreads();
    #pragma unroll
    for (int ti = 0; ti < 2; ++ti)
      #pragma unroll
      for (int h = 0; h < HEADS; ++h) {
        const int idx = ti * 4 + h;
        inv[ti][h] = 0.25f / (s_reds[idx][0] + s_reds[idx][1] + s_reds[idx][2] + s_reds[idx][3]);
      }

    #pragma unroll
    for (int ti = 0; ti < 2; ++ti) {
      float4 o;
      o.x = sc[ti][0].x * inv[ti][0] + sc[ti][1].x * inv[ti][1] +
            sc[ti][2].x * inv[ti][2] + sc[ti][3].x * inv[ti][3];
      o.y = sc[ti][0].y * inv[ti][0] + sc[ti][1].y * inv[ti][1] +
            sc[ti][2].y * inv[ti][2] + sc[ti][3].y * inv[ti][3];
      o.z = sc[ti][0].z * inv[ti][0] + sc[ti][1].z * inv[ti][1] +
            sc[ti][2].z * inv[ti][2] + sc[ti][3].z * inv[ti][3];
      o.w = sc[ti][0].w * inv[ti][0] + sc[ti][1].w * inv[ti][1] +
            sc[ti][2].w * inv[ti][2] + sc[ti][3].w * inv[ti][3];
      ((float4*)(out0 + (size_t)(i0 + ti) * N))[t] = o;
    }
    return;
  }

  // ---------------- classifier path ----------------
  {
    float (*s_ac)[64] = (float(*)[64])s_buf;
    const int i0 = (b - PAIR_BLOCKS - ATTN_BLOCKS) * 2;
    if (t < 128)
      s_ac[t >> 6][t & 63] = sa_c[(i0 + (t >> 6)) * 64 + (t & 63)] + cb1[t & 63];
    __syncthreads();

    const float4* sbc4 = (const float4*)sb_cT;
    float4 ac0 = {0.f, 0.f, 0.f, 0.f}, ac1 = {0.f, 0.f, 0.f, 0.f};
    #pragma unroll 4
    for (int k = 0; k < 64; ++k) {
      const float4 sb = sbc4[k * 256 + t];
      const float a0 = s_ac[0][k], a1 = s_ac[1][k];
      const float we = cw2[k];
      ac0.x = fmaf(fmaxf(a0 + sb.x, 0.f), we, ac0.x);
      ac0.y = fmaf(fmaxf(a0 + sb.y, 0.f), we, ac0.y);
      ac0.z = fmaf(fmaxf(a0 + sb.z, 0.f), we, ac0.z);
      ac0.w = fmaf(fmaxf(a0 + sb.w, 0.f), we, ac0.w);
      ac1.x = fmaf(fmaxf(a1 + sb.x, 0.f), we, ac1.x);
      ac1.y = fmaf(fmaxf(a1 + sb.y, 0.f), we, ac1.y);
      ac1.z = fmaf(fmaxf(a1 + sb.z, 0.f), we, ac1.z);
      ac1.w = fmaf(fmaxf(a1 + sb.w, 0.f), we, ac1.w);
    }
    const float cb = cb2[0];
    float4 o0, o1;
    o0.x = 1.f / (1.f + __expf(-(ac0.x + cb)));
    o0.y = 1.f / (1.f + __expf(-(ac0.y + cb)));
    o0.z = 1.f / (1.f + __expf(-(ac0.z + cb)));
    o0.w = 1.f / (1.f + __expf(-(ac0.w + cb)));
    o1.x = 1.f / (1.f + __expf(-(ac1.x + cb)));
    o1.y = 1.f / (1.f + __expf(-(ac1.y + cb)));
    o1.z = 1.f / (1.f + __expf(-(ac1.z + cb)));
    o1.w = 1.f / (1.f + __expf(-(ac1.w + cb)));
    ((float4*)(out1 + (size_t)i0 * N))[t] = o0;
    ((float4*)(out1 + (size_t)(i0 + 1) * N))[t] = o1;
  }
}

extern "C" void kernel_launch(void* const* d_in, const int* in_sizes, int n_in,
                              void* d_out, int out_size, void* d_ws, size_t ws_size,
                              hipStream_t stream) {
  const float* nf  = (const float*)d_in[0];
  const float* ew1 = (const float*)d_in[1];
  const float* eb1 = (const float*)d_in[2];
  const float* ew2 = (const float*)d_in[3];
  const float* eb2 = (const float*)d_in[4];
  const float* ipw = (const float*)d_in[5];
  const float* ipb = (const float*)d_in[6];
  const float* pw1 = (const float*)d_in[7];
  const float* pb1 = (const float*)d_in[8];
  const float* pw2 = (const float*)d_in[9];
  const float* pb2 = (const float*)d_in[10];
  const float* cw1 = (const float*)d_in[11];
  const float* cb1 = (const float*)d_in[12];
  const float* cw2 = (const float*)d_in[13];
  const float* cb2 = (const float*)d_in[14];

  float* ws = (float*)d_ws;
  float* q     = ws + 131072;        // 1024*128
  float* kkT   = ws + 262144;        // 128*1024 (transposed)
  float* sa_pb = ws + 393216;        // 1024*128 (pb1 folded)
  float* sb_ps = ws + 524288;        // 1024*128 (MFMA-swizzled)
  float* sa_c  = ws + 655360;        // 1024*64
  float* sb_cT = ws + 720896;        // 64*1024 (transposed)
  unsigned short* w2f = (unsigned short*)(ws + 786432);  // 8*64*8 bf16

  float* out0 = (float*)d_out;             // attention_weights [1024*1024]
  float* out1 = out0 + N * N;              // edge_probabilities [1024*1024]
  float* out2 = out0 + 2 * N * N;          // predicted_edge_features [1024*1024*17]

  k_front<<<513, 256, 0, stream>>>(nf, ew1, eb1, ew2, eb2, ipw, ipb, pw1, pb1, cw1, pw2,
                                   q, kkT, sa_pb, sb_ps, sa_c, sb_cT, w2f);
  k_main<<<PAIR_BLOCKS + ATTN_BLOCKS + CLS_BLOCKS, 256, 0, stream>>>(
      sa_pb, sb_ps, w2f, pb2, q, kkT, sa_c, sb_cT, cb1, cw2, cb2, out0, out1, out2);
}

// Round 21
// 67.239 us; speedup vs baseline: 1.1165x; 1.1165x over previous
//
#include <hip/hip_runtime.h>
#include <hip/hip_bf16.h>

// Problem constants
#define N 1024
#define NF 27
#define EF 17
#define H 128
#define HEADS 4
#define HD 32

typedef __attribute__((ext_vector_type(8))) short bf16x8;
typedef __attribute__((ext_vector_type(16))) float f32x16;

__device__ __forceinline__ short f2bf(float x) {
  return __builtin_bit_cast(short, __float2bfloat16(x));
}
__device__ __forceinline__ unsigned pk2bf(float a, float b) {
  const unsigned lo = (unsigned short)f2bf(a);
  const unsigned hi = (unsigned short)f2bf(b);
  return lo | (hi << 16);
}

// =================== FRONT: prep + encoder + projections (fused, 2 rows/block) ===================
__global__ __launch_bounds__(256) void k_front(
    const float* __restrict__ nf,
    const float* __restrict__ ew1, const float* __restrict__ eb1,
    const float* __restrict__ ew2, const float* __restrict__ eb2,
    const float* __restrict__ ipw, const float* __restrict__ ipb,
    const float* __restrict__ pw1, const float* __restrict__ pb1,
    const float* __restrict__ cw1, const float* __restrict__ pw2,
    float* __restrict__ q, float* __restrict__ kkT,
    float* __restrict__ sa_pb, float* __restrict__ sb_ps,
    float* __restrict__ sa_c, float* __restrict__ sb_cT,
    unsigned short* __restrict__ w2f)
{
  const int t = threadIdx.x;
  if (blockIdx.x == 512) {
    // ---- prepack pw2 ----
    if (t < 64) {
      const int lane = t, col = lane & 31, hsel = lane >> 5;
      for (int kc = 0; kc < 8; ++kc)
        for (int e = 0; e < 8; ++e) {
          const int k = kc * 16 + hsel * 8 + e;
          w2f[(kc * 64 + lane) * 8 + e] =
              (unsigned short)((col < EF) ? (unsigned short)f2bf(pw2[k * EF + col]) : 0);
        }
    }
    return;
  }

  __shared__ float s_nf[2 * NF];
  __shared__ float s_h1[2][H];
  __shared__ float s_e[2][H];
  const int i0 = blockIdx.x * 2;
  if (t < 2 * NF) s_nf[t] = nf[i0 * NF + t];
  __syncthreads();

  // encoder for 2 rows: thread (ti = t>>7, c = t&127)
  {
    const int ti = t >> 7, c = t & 127;
    float h = eb1[c];
    #pragma unroll
    for (int f = 0; f < NF; ++f) h = fmaf(s_nf[ti * NF + f], ew1[f * H + c], h);
    s_h1[ti][c] = fmaxf(h, 0.f);
  }
  __syncthreads();
  {
    const int ti = t >> 7, c = t & 127;
    float e = eb2[c];
    #pragma unroll 8
    for (int k = 0; k < H; ++k) e = fmaf(s_h1[ti][k], ew2[k * H + c], e);
    s_e[ti][c] = e;
  }
  __syncthreads();

  // projections (2 rows at once; weight stream amortized)
  for (int c = t; c < 640; c += 256) {
    float a0, a1;
    if (c < 256) {
      a0 = ipb[c]; a1 = a0;
      const float* wcol = ipw + c;
      #pragma unroll 8
      for (int k = 0; k < H; ++k) {
        const float w = wcol[k * 384];
        a0 = fmaf(s_e[0][k], w, a0); a1 = fmaf(s_e[1][k], w, a1);
      }
      if (c < 128) { q[i0 * H + c] = a0; q[(i0 + 1) * H + c] = a1; }
      else { kkT[(c - 128) * N + i0] = a0; kkT[(c - 128) * N + i0 + 1] = a1; }
    } else if (c < 512) {
      const int cc = (c < 384) ? (c - 256) : (c - 384);
      const float* wcol = (c < 384) ? (pw1 + cc) : (pw1 + 128 * H + cc);
      a0 = 0.f; a1 = 0.f;
      #pragma unroll 8
      for (int k = 0; k < H; ++k) {
        const float w = wcol[k * H];
        a0 = fmaf(s_e[0][k], w, a0); a1 = fmaf(s_e[1][k], w, a1);
      }
      if (c < 384) {
        const float b = pb1[cc];
        sa_pb[i0 * H + cc] = a0 + b;
        sa_pb[(i0 + 1) * H + cc] = a1 + b;
      } else {
        const int J = i0 >> 5, jl = i0 & 31;
        const int kc = cc >> 4, hs = (cc >> 3) & 1, hf = (cc >> 2) & 1, pos = cc & 3;
        const int base = ((J * 32 + kc * 4 + hs * 2 + hf) * 32) * 4 + pos;
        sb_ps[base + jl * 4] = a0;
        sb_ps[base + (jl + 1) * 4] = a1;
      }
    } else {
      const int cc = (c < 576) ? (c - 512) : (c - 576);
      const float* wcol = (c < 576) ? (cw1 + cc) : (cw1 + 128 * 64 + cc);
      a0 = 0.f; a1 = 0.f;
      #pragma unroll 8
      for (int k = 0; k < H; ++k) {
        const float w = wcol[k * 64];
        a0 = fmaf(s_e[0][k], w, a0); a1 = fmaf(s_e[1][k], w, a1);
      }
      if (c < 576) { sa_c[i0 * 64 + cc] = a0; sa_c[(i0 + 1) * 64 + cc] = a1; }
      else { sb_cT[cc * N + i0] = a0; sb_cT[cc * N + i0 + 1] = a1; }
    }
  }
}

// =================== MAIN: pair (0..4095) || attn (4096..4607) || cls (4608..5119) ===================
#define PAIR_BLOCKS 4096
#define ATTN_BLOCKS 512
#define CLS_BLOCKS  512

__global__ __launch_bounds__(256) void k_main(
    const float* __restrict__ sa_pb, const float* __restrict__ sb_ps,
    const unsigned short* __restrict__ w2f, const float* __restrict__ pb2,
    const float* __restrict__ q, const float* __restrict__ kkT,
    const float* __restrict__ sa_c, const float* __restrict__ sb_cT,
    const float* __restrict__ cb1, const float* __restrict__ cw2, const float* __restrict__ cb2,
    float* __restrict__ out0, float* __restrict__ out1, float* __restrict__ out2)
{
  __shared__ float4 s_buf[1280];   // 20 KB union across paths
  const int t = threadIdx.x;
  const int b = blockIdx.x;

  if (b < PAIR_BLOCKS) {
    // ---------------- pair path (kc-outer, 2 acc chains) ----------------
    float4* s_sb = s_buf;                       // 1024 float4
    float*  s_ap = (float*)(s_buf + 1024);      // 8*H floats

    const int lane = t & 63, wid = t >> 6;
    const int It = b >> 5;     // 0..127 (8 i's each)
    const int J  = b & 31;     // j-tile (32 j's)
    const int i0 = It * 8;
    const int col = lane & 31, hsel = lane >> 5;

    const float4* g_sb = ((const float4*)sb_ps) + J * 1024;
    #pragma unroll
    for (int c = t; c < 1024; c += 256) s_sb[c] = g_sb[c];
    ((float4*)s_ap)[t] = ((const float4*)(sa_pb + i0 * H))[t];

    const bf16x8* w2f8 = (const bf16x8*)w2f;
    bf16x8 bfrag[8];
    #pragma unroll
    for (int kc = 0; kc < 8; ++kc) bfrag[kc] = w2f8[kc * 64 + lane];
    const float pb2c = (col < EF) ? pb2[col] : 0.f;
    __syncthreads();

    const int ia = wid * 2, ib = ia + 1;
    f32x16 accA, accB;
    #pragma unroll
    for (int r = 0; r < 16; ++r) { accA[r] = 0.f; accB[r] = 0.f; }

    #pragma unroll
    for (int kc = 0; kc < 8; ++kc) {
      const int cl = (kc * 4 + hsel * 2) * 32 + col;
      const float4 v0 = s_sb[cl];
      const float4 v1 = s_sb[cl + 32];
      const float* apA = s_ap + ia * H + kc * 16 + hsel * 8;
      const float* apB = s_ap + ib * H + kc * 16 + hsel * 8;
      const float4 a0 = *(const float4*)apA;
      const float4 a1 = *(const float4*)(apA + 4);
      const float4 b0 = *(const float4*)apB;
      const float4 b1 = *(const float4*)(apB + 4);
      union { bf16x8 v8; unsigned u[4]; } uA, uB;
      uA.u[0] = pk2bf(fmaxf(a0.x + v0.x, 0.f), fmaxf(a0.y + v0.y, 0.f));
      uA.u[1] = pk2bf(fmaxf(a0.z + v0.z, 0.f), fmaxf(a0.w + v0.w, 0.f));
      uA.u[2] = pk2bf(fmaxf(a1.x + v1.x, 0.f), fmaxf(a1.y + v1.y, 0.f));
      uA.u[3] = pk2bf(fmaxf(a1.z + v1.z, 0.f), fmaxf(a1.w + v1.w, 0.f));
      uB.u[0] = pk2bf(fmaxf(b0.x + v0.x, 0.f), fmaxf(b0.y + v0.y, 0.f));
      uB.u[1] = pk2bf(fmaxf(b0.z + v0.z, 0.f), fmaxf(b0.w + v0.w, 0.f));
      uB.u[2] = pk2bf(fmaxf(b1.x + v1.x, 0.f), fmaxf(b1.y + v1.y, 0.f));
      uB.u[3] = pk2bf(fmaxf(b1.z + v1.z, 0.f), fmaxf(b1.w + v1.w, 0.f));
      accA = __builtin_amdgcn_mfma_f32_32x32x16_bf16(uA.v8, bfrag[kc], accA, 0, 0, 0);
      accB = __builtin_amdgcn_mfma_f32_32x32x16_bf16(uB.v8, bfrag[kc], accB, 0, 0, 0);
    }

    if (col < EF) {
      const int jbase = J * 32 + 4 * hsel;
      float* oA = out2 + ((size_t)(i0 + ia) * N + jbase) * EF + col;
      float* oB = out2 + ((size_t)(i0 + ib) * N + jbase) * EF + col;
      #pragma unroll
      for (int r = 0; r < 16; ++r) {
        const int off = ((r & 3) + 8 * (r >> 2)) * EF;
        oA[off] = accA[r] + pb2c;
        oB[off] = accB[r] + pb2c;
      }
    }
    return;
  }

  if (b < PAIR_BLOCKS + ATTN_BLOCKS) {
    // ---------------- attention path ----------------
    float (*s_q)[H] = (float(*)[H])s_buf;
    float (*s_redm)[4] = (float(*)[4])((float*)s_buf + 2 * H);
    float (*s_reds)[4] = (float(*)[4])((float*)s_buf + 2 * H + 32);

    const int i0 = (b - PAIR_BLOCKS) * 2;
    const int w = t >> 6, lane = t & 63;
    s_q[t >> 7][t & 127] = q[(i0 + (t >> 7)) * H + (t & 127)];
    __syncthreads();

    const float scale = 0.17677669529663687f;  // 1/sqrt(32)
    const float4* kT4 = (const float4*)kkT;
    float4 sc[2][4];

    #pragma unroll
    for (int h = 0; h < HEADS; ++h) {
      float4 a0 = {0.f, 0.f, 0.f, 0.f}, a1 = {0.f, 0.f, 0.f, 0.f};
      #pragma unroll 8
      for (int d = 0; d < HD; ++d) {
        const float4 kv = kT4[(h * HD + d) * 256 + t];
        const float q0 = s_q[0][h * HD + d], q1 = s_q[1][h * HD + d];
        a0.x = fmaf(q0, kv.x, a0.x); a0.y = fmaf(q0, kv.y, a0.y);
        a0.z = fmaf(q0, kv.z, a0.z); a0.w = fmaf(q0, kv.w, a0.w);
        a1.x = fmaf(q1, kv.x, a1.x); a1.y = fmaf(q1, kv.y, a1.y);
        a1.z = fmaf(q1, kv.z, a1.z); a1.w = fmaf(q1, kv.w, a1.w);
      }
      sc[0][h].x = a0.x * scale; sc[0][h].y = a0.y * scale;
      sc[0][h].z = a0.z * scale; sc[0][h].w = a0.w * scale;
      sc[1][h].x = a1.x * scale; sc[1][h].y = a1.y * scale;
      sc[1][h].z = a1.z * scale; sc[1][h].w = a1.w * scale;
    }

    float m[2][4];
    #pragma unroll
    for (int ti = 0; ti < 2; ++ti)
      #pragma unroll
      for (int h = 0; h < HEADS; ++h) {
        float mm = fmaxf(fmaxf(sc[ti][h].x, sc[ti][h].y), fmaxf(sc[ti][h].z, sc[ti][h].w));
        for (int off = 32; off; off >>= 1) mm = fmaxf(mm, __shfl_xor(mm, off));
        if (lane == 0) s_redm[ti * 4 + h][w] = mm;
      }
    __syncthreads();
    #pragma unroll
    for (int ti = 0; ti < 2; ++ti)
      #pragma unroll
      for (int h = 0; h < HEADS; ++h) {
        const int idx = ti * 4 + h;
        m[ti][h] = fmaxf(fmaxf(s_redm[idx][0], s_redm[idx][1]),
                         fmaxf(s_redm[idx][2], s_redm[idx][3]));
      }

    float inv[2][4];
    #pragma unroll
    for (int ti = 0; ti < 2; ++ti)
      #pragma unroll
      for (int h = 0; h < HEADS; ++h) {
        sc[ti][h].x = __expf(sc[ti][h].x - m[ti][h]);
        sc[ti][h].y = __expf(sc[ti][h].y - m[ti][h]);
        sc[ti][h].z = __expf(sc[ti][h].z - m[ti][h]);
        sc[ti][h].w = __expf(sc[ti][h].w - m[ti][h]);
        float s = sc[ti][h].x + sc[ti][h].y + sc[ti][h].z + sc[ti][h].w;
        for (int off = 32; off; off >>= 1) s += __shfl_xor(s, off);
        if (lane == 0) s_reds[ti * 4 + h][w] = s;
      }
    __syncthreads();
    #pragma unroll
    for (int ti = 0; ti < 2; ++ti)
      #pragma unroll
      for (int h = 0; h < HEADS; ++h) {
        const int idx = ti * 4 + h;
        inv[ti][h] = 0.25f / (s_reds[idx][0] + s_reds[idx][1] + s_reds[idx][2] + s_reds[idx][3]);
      }

    #pragma unroll
    for (int ti = 0; ti < 2; ++ti) {
      float4 o;
      o.x = sc[ti][0].x * inv[ti][0] + sc[ti][1].x * inv[ti][1] +
            sc[ti][2].x * inv[ti][2] + sc[ti][3].x * inv[ti][3];
      o.y = sc[ti][0].y * inv[ti][0] + sc[ti][1].y * inv[ti][1] +
            sc[ti][2].y * inv[ti][2] + sc[ti][3].y * inv[ti][3];
      o.z = sc[ti][0].z * inv[ti][0] + sc[ti][1].z * inv[ti][1] +
            sc[ti][2].z * inv[ti][2] + sc[ti][3].z * inv[ti][3];
      o.w = sc[ti][0].w * inv[ti][0] + sc[ti][1].w * inv[ti][1] +
            sc[ti][2].w * inv[ti][2] + sc[ti][3].w * inv[ti][3];
      ((float4*)(out0 + (size_t)(i0 + ti) * N))[t] = o;
    }
    return;
  }

  // ---------------- classifier path ----------------
  {
    float (*s_ac)[64] = (float(*)[64])s_buf;
    const int i0 = (b - PAIR_BLOCKS - ATTN_BLOCKS) * 2;
    if (t < 128)
      s_ac[t >> 6][t & 63] = sa_c[(i0 + (t >> 6)) * 64 + (t & 63)] + cb1[t & 63];
    __syncthreads();

    const float4* sbc4 = (const float4*)sb_cT;
    float4 ac0 = {0.f, 0.f, 0.f, 0.f}, ac1 = {0.f, 0.f, 0.f, 0.f};
    #pragma unroll 4
    for (int k = 0; k < 64; ++k) {
      const float4 sb = sbc4[k * 256 + t];
      const float a0 = s_ac[0][k], a1 = s_ac[1][k];
      const float we = cw2[k];
      ac0.x = fmaf(fmaxf(a0 + sb.x, 0.f), we, ac0.x);
      ac0.y = fmaf(fmaxf(a0 + sb.y, 0.f), we, ac0.y);
      ac0.z = fmaf(fmaxf(a0 + sb.z, 0.f), we, ac0.z);
      ac0.w = fmaf(fmaxf(a0 + sb.w, 0.f), we, ac0.w);
      ac1.x = fmaf(fmaxf(a1 + sb.x, 0.f), we, ac1.x);
      ac1.y = fmaf(fmaxf(a1 + sb.y, 0.f), we, ac1.y);
      ac1.z = fmaf(fmaxf(a1 + sb.z, 0.f), we, ac1.z);
      ac1.w = fmaf(fmaxf(a1 + sb.w, 0.f), we, ac1.w);
    }
    const float cb = cb2[0];
    float4 o0, o1;
    o0.x = 1.f / (1.f + __expf(-(ac0.x + cb)));
    o0.y = 1.f / (1.f + __expf(-(ac0.y + cb)));
    o0.z = 1.f / (1.f + __expf(-(ac0.z + cb)));
    o0.w = 1.f / (1.f + __expf(-(ac0.w + cb)));
    o1.x = 1.f / (1.f + __expf(-(ac1.x + cb)));
    o1.y = 1.f / (1.f + __expf(-(ac1.y + cb)));
    o1.z = 1.f / (1.f + __expf(-(ac1.z + cb)));
    o1.w = 1.f / (1.f + __expf(-(ac1.w + cb)));
    ((float4*)(out1 + (size_t)i0 * N))[t] = o0;
    ((float4*)(out1 + (size_t)(i0 + 1) * N))[t] = o1;
  }
}

extern "C" void kernel_launch(void* const* d_in, const int* in_sizes, int n_in,
                              void* d_out, int out_size, void* d_ws, size_t ws_size,
                              hipStream_t stream) {
  const float* nf  = (const float*)d_in[0];
  const float* ew1 = (const float*)d_in[1];
  const float* eb1 = (const float*)d_in[2];
  const float* ew2 = (const float*)d_in[3];
  const float* eb2 = (const float*)d_in[4];
  const float* ipw = (const float*)d_in[5];
  const float* ipb = (const float*)d_in[6];
  const float* pw1 = (const float*)d_in[7];
  const float* pb1 = (const float*)d_in[8];
  const float* pw2 = (const float*)d_in[9];
  const float* pb2 = (const float*)d_in[10];
  const float* cw1 = (const float*)d_in[11];
  const float* cb1 = (const float*)d_in[12];
  const float* cw2 = (const float*)d_in[13];
  const float* cb2 = (const float*)d_in[14];

  float* ws = (float*)d_ws;
  float* q     = ws + 131072;        // 1024*128
  float* kkT   = ws + 262144;        // 128*1024 (transposed)
  float* sa_pb = ws + 393216;        // 1024*128 (pb1 folded)
  float* sb_ps = ws + 524288;        // 1024*128 (MFMA-swizzled)
  float* sa_c  = ws + 655360;        // 1024*64
  float* sb_cT = ws + 720896;        // 64*1024 (transposed)
  unsigned short* w2f = (unsigned short*)(ws + 786432);  // 8*64*8 bf16

  float* out0 = (float*)d_out;             // attention_weights [1024*1024]
  float* out1 = out0 + N * N;              // edge_probabilities [1024*1024]
  float* out2 = out0 + 2 * N * N;          // predicted_edge_features [1024*1024*17]

  k_front<<<513, 256, 0, stream>>>(nf, ew1, eb1, ew2, eb2, ipw, ipb, pw1, pb1, cw1, pw2,
                                   q, kkT, sa_pb, sb_ps, sa_c, sb_cT, w2f);
  k_main<<<PAIR_BLOCKS + ATTN_BLOCKS + CLS_BLOCKS, 256, 0, stream>>>(
      sa_pb, sb_ps, w2f, pb2, q, kkT, sa_c, sb_cT, cb1, cw2, cb2, out0, out1, out2);
}

// Round 22
// 66.593 us; speedup vs baseline: 1.1273x; 1.0097x over previous
//
#include <hip/hip_runtime.h>
#include <hip/hip_bf16.h>

// Problem constants
#define N 1024
#define NF 27
#define EF 17
#define H 128
#define HEADS 4
#define HD 32

typedef __attribute__((ext_vector_type(8))) short bf16x8;
typedef __attribute__((ext_vector_type(16))) float f32x16;

__device__ __forceinline__ short f2bf(float x) {
  return __builtin_bit_cast(short, __float2bfloat16(x));
}
__device__ __forceinline__ unsigned pk2bf(float a, float b) {
  const unsigned lo = (unsigned short)f2bf(a);
  const unsigned hi = (unsigned short)f2bf(b);
  return lo | (hi << 16);
}

// =================== FRONT: prep + encoder + projections (fused, 2 rows/block) ===================
__global__ __launch_bounds__(256) void k_front(
    const float* __restrict__ nf,
    const float* __restrict__ ew1, const float* __restrict__ eb1,
    const float* __restrict__ ew2, const float* __restrict__ eb2,
    const float* __restrict__ ipw, const float* __restrict__ ipb,
    const float* __restrict__ pw1, const float* __restrict__ pb1,
    const float* __restrict__ cw1, const float* __restrict__ pw2,
    float* __restrict__ q, float* __restrict__ kkT,
    float* __restrict__ sa_pb, float* __restrict__ sb_ps,
    float* __restrict__ sa_c, float* __restrict__ sb_cT,
    unsigned short* __restrict__ w2f)
{
  const int t = threadIdx.x;
  if (blockIdx.x == 512) {
    // ---- prepack pw2 ----
    if (t < 64) {
      const int lane = t, col = lane & 31, hsel = lane >> 5;
      for (int kc = 0; kc < 8; ++kc)
        for (int e = 0; e < 8; ++e) {
          const int k = kc * 16 + hsel * 8 + e;
          w2f[(kc * 64 + lane) * 8 + e] =
              (unsigned short)((col < EF) ? (unsigned short)f2bf(pw2[k * EF + col]) : 0);
        }
    }
    return;
  }

  __shared__ float s_nf[2 * NF];
  __shared__ float s_h1[2][H];
  __shared__ float s_e[2][H];
  const int i0 = blockIdx.x * 2;
  if (t < 2 * NF) s_nf[t] = nf[i0 * NF + t];
  __syncthreads();

  // encoder for 2 rows: thread (ti = t>>7, c = t&127)
  {
    const int ti = t >> 7, c = t & 127;
    float h = eb1[c];
    #pragma unroll
    for (int f = 0; f < NF; ++f) h = fmaf(s_nf[ti * NF + f], ew1[f * H + c], h);
    s_h1[ti][c] = fmaxf(h, 0.f);
  }
  __syncthreads();
  {
    const int ti = t >> 7, c = t & 127;
    float e = eb2[c];
    #pragma unroll 8
    for (int k = 0; k < H; ++k) e = fmaf(s_h1[ti][k], ew2[k * H + c], e);
    s_e[ti][c] = e;
  }
  __syncthreads();

  // projections (2 rows at once; weight stream amortized)
  for (int c = t; c < 640; c += 256) {
    float a0, a1;
    if (c < 256) {
      a0 = ipb[c]; a1 = a0;
      const float* wcol = ipw + c;
      #pragma unroll 8
      for (int k = 0; k < H; ++k) {
        const float w = wcol[k * 384];
        a0 = fmaf(s_e[0][k], w, a0); a1 = fmaf(s_e[1][k], w, a1);
      }
      if (c < 128) { q[i0 * H + c] = a0; q[(i0 + 1) * H + c] = a1; }
      else { kkT[(c - 128) * N + i0] = a0; kkT[(c - 128) * N + i0 + 1] = a1; }
    } else if (c < 512) {
      const int cc = (c < 384) ? (c - 256) : (c - 384);
      const float* wcol = (c < 384) ? (pw1 + cc) : (pw1 + 128 * H + cc);
      a0 = 0.f; a1 = 0.f;
      #pragma unroll 8
      for (int k = 0; k < H; ++k) {
        const float w = wcol[k * H];
        a0 = fmaf(s_e[0][k], w, a0); a1 = fmaf(s_e[1][k], w, a1);
      }
      if (c < 384) {
        const float b = pb1[cc];
        sa_pb[i0 * H + cc] = a0 + b;
        sa_pb[(i0 + 1) * H + cc] = a1 + b;
      } else {
        const int J = i0 >> 5, jl = i0 & 31;
        const int kc = cc >> 4, hs = (cc >> 3) & 1, hf = (cc >> 2) & 1, pos = cc & 3;
        const int base = ((J * 32 + kc * 4 + hs * 2 + hf) * 32) * 4 + pos;
        sb_ps[base + jl * 4] = a0;
        sb_ps[base + (jl + 1) * 4] = a1;
      }
    } else {
      const int cc = (c < 576) ? (c - 512) : (c - 576);
      const float* wcol = (c < 576) ? (cw1 + cc) : (cw1 + 128 * 64 + cc);
      a0 = 0.f; a1 = 0.f;
      #pragma unroll 8
      for (int k = 0; k < H; ++k) {
        const float w = wcol[k * 64];
        a0 = fmaf(s_e[0][k], w, a0); a1 = fmaf(s_e[1][k], w, a1);
      }
      if (c < 576) { sa_c[i0 * 64 + cc] = a0; sa_c[(i0 + 1) * 64 + cc] = a1; }
      else { sb_cT[cc * N + i0] = a0; sb_cT[cc * N + i0 + 1] = a1; }
    }
  }
}

// =================== MAIN: attn (0..511) | cls (512..1023) | pair (1024..5119) ===================
#define ATTN_BLOCKS 512
#define CLS_BLOCKS  512
#define PAIR_BLOCKS 4096

__global__ __launch_bounds__(256) void k_main(
    const float* __restrict__ sa_pb, const float* __restrict__ sb_ps,
    const unsigned short* __restrict__ w2f, const float* __restrict__ pb2,
    const float* __restrict__ q, const float* __restrict__ kkT,
    const float* __restrict__ sa_c, const float* __restrict__ sb_cT,
    const float* __restrict__ cb1, const float* __restrict__ cw2, const float* __restrict__ cb2,
    float* __restrict__ out0, float* __restrict__ out1, float* __restrict__ out2)
{
  __shared__ float4 s_buf[1280];   // 20 KB union across paths
  const int t = threadIdx.x;
  const int b = blockIdx.x;

  if (b >= ATTN_BLOCKS + CLS_BLOCKS) {
    // ---------------- pair path (kc-outer, 2 acc chains) ----------------
    const int pb = b - (ATTN_BLOCKS + CLS_BLOCKS);
    float4* s_sb = s_buf;                       // 1024 float4
    float*  s_ap = (float*)(s_buf + 1024);      // 8*H floats

    const int lane = t & 63, wid = t >> 6;
    const int It = pb >> 5;     // 0..127 (8 i's each)
    const int J  = pb & 31;     // j-tile (32 j's)
    const int i0 = It * 8;
    const int col = lane & 31, hsel = lane >> 5;

    const float4* g_sb = ((const float4*)sb_ps) + J * 1024;
    #pragma unroll
    for (int c = t; c < 1024; c += 256) s_sb[c] = g_sb[c];
    ((float4*)s_ap)[t] = ((const float4*)(sa_pb + i0 * H))[t];

    const bf16x8* w2f8 = (const bf16x8*)w2f;
    bf16x8 bfrag[8];
    #pragma unroll
    for (int kc = 0; kc < 8; ++kc) bfrag[kc] = w2f8[kc * 64 + lane];
    const float pb2c = (col < EF) ? pb2[col] : 0.f;
    __syncthreads();

    const int ia = wid * 2, ib = ia + 1;
    f32x16 accA, accB;
    #pragma unroll
    for (int r = 0; r < 16; ++r) { accA[r] = 0.f; accB[r] = 0.f; }

    #pragma unroll
    for (int kc = 0; kc < 8; ++kc) {
      const int cl = (kc * 4 + hsel * 2) * 32 + col;
      const float4 v0 = s_sb[cl];
      const float4 v1 = s_sb[cl + 32];
      const float* apA = s_ap + ia * H + kc * 16 + hsel * 8;
      const float* apB = s_ap + ib * H + kc * 16 + hsel * 8;
      const float4 a0 = *(const float4*)apA;
      const float4 a1 = *(const float4*)(apA + 4);
      const float4 b0 = *(const float4*)apB;
      const float4 b1 = *(const float4*)(apB + 4);
      union { bf16x8 v8; unsigned u[4]; } uA, uB;
      uA.u[0] = pk2bf(fmaxf(a0.x + v0.x, 0.f), fmaxf(a0.y + v0.y, 0.f));
      uA.u[1] = pk2bf(fmaxf(a0.z + v0.z, 0.f), fmaxf(a0.w + v0.w, 0.f));
      uA.u[2] = pk2bf(fmaxf(a1.x + v1.x, 0.f), fmaxf(a1.y + v1.y, 0.f));
      uA.u[3] = pk2bf(fmaxf(a1.z + v1.z, 0.f), fmaxf(a1.w + v1.w, 0.f));
      uB.u[0] = pk2bf(fmaxf(b0.x + v0.x, 0.f), fmaxf(b0.y + v0.y, 0.f));
      uB.u[1] = pk2bf(fmaxf(b0.z + v0.z, 0.f), fmaxf(b0.w + v0.w, 0.f));
      uB.u[2] = pk2bf(fmaxf(b1.x + v1.x, 0.f), fmaxf(b1.y + v1.y, 0.f));
      uB.u[3] = pk2bf(fmaxf(b1.z + v1.z, 0.f), fmaxf(b1.w + v1.w, 0.f));
      accA = __builtin_amdgcn_mfma_f32_32x32x16_bf16(uA.v8, bfrag[kc], accA, 0, 0, 0);
      accB = __builtin_amdgcn_mfma_f32_32x32x16_bf16(uB.v8, bfrag[kc], accB, 0, 0, 0);
    }

    if (col < EF) {
      const int jbase = J * 32 + 4 * hsel;
      float* oA = out2 + ((size_t)(i0 + ia) * N + jbase) * EF + col;
      float* oB = out2 + ((size_t)(i0 + ib) * N + jbase) * EF + col;
      #pragma unroll
      for (int r = 0; r < 16; ++r) {
        const int off = ((r & 3) + 8 * (r >> 2)) * EF;
        oA[off] = accA[r] + pb2c;
        oB[off] = accB[r] + pb2c;
      }
    }
    return;
  }

  if (b < ATTN_BLOCKS) {
    // ---------------- attention path ----------------
    float (*s_q)[H] = (float(*)[H])s_buf;
    float (*s_redm)[4] = (float(*)[4])((float*)s_buf + 2 * H);
    float (*s_reds)[4] = (float(*)[4])((float*)s_buf + 2 * H + 32);

    const int i0 = b * 2;
    const int w = t >> 6, lane = t & 63;
    s_q[t >> 7][t & 127] = q[(i0 + (t >> 7)) * H + (t & 127)];
    __syncthreads();

    const float scale = 0.17677669529663687f;  // 1/sqrt(32)
    const float4* kT4 = (const float4*)kkT;
    float4 sc[2][4];

    #pragma unroll
    for (int h = 0; h < HEADS; ++h) {
      float4 a0 = {0.f, 0.f, 0.f, 0.f}, a1 = {0.f, 0.f, 0.f, 0.f};
      #pragma unroll 8
      for (int d = 0; d < HD; ++d) {
        const float4 kv = kT4[(h * HD + d) * 256 + t];
        const float q0 = s_q[0][h * HD + d], q1 = s_q[1][h * HD + d];
        a0.x = fmaf(q0, kv.x, a0.x); a0.y = fmaf(q0, kv.y, a0.y);
        a0.z = fmaf(q0, kv.z, a0.z); a0.w = fmaf(q0, kv.w, a0.w);
        a1.x = fmaf(q1, kv.x, a1.x); a1.y = fmaf(q1, kv.y, a1.y);
        a1.z = fmaf(q1, kv.z, a1.z); a1.w = fmaf(q1, kv.w, a1.w);
      }
      sc[0][h].x = a0.x * scale; sc[0][h].y = a0.y * scale;
      sc[0][h].z = a0.z * scale; sc[0][h].w = a0.w * scale;
      sc[1][h].x = a1.x * scale; sc[1][h].y = a1.y * scale;
      sc[1][h].z = a1.z * scale; sc[1][h].w = a1.w * scale;
    }

    float m[2][4];
    #pragma unroll
    for (int ti = 0; ti < 2; ++ti)
      #pragma unroll
      for (int h = 0; h < HEADS; ++h) {
        float mm = fmaxf(fmaxf(sc[ti][h].x, sc[ti][h].y), fmaxf(sc[ti][h].z, sc[ti][h].w));
        for (int off = 32; off; off >>= 1) mm = fmaxf(mm, __shfl_xor(mm, off));
        if (lane == 0) s_redm[ti * 4 + h][w] = mm;
      }
    __syncthreads();
    #pragma unroll
    for (int ti = 0; ti < 2; ++ti)
      #pragma unroll
      for (int h = 0; h < HEADS; ++h) {
        const int idx = ti * 4 + h;
        m[ti][h] = fmaxf(fmaxf(s_redm[idx][0], s_redm[idx][1]),
                         fmaxf(s_redm[idx][2], s_redm[idx][3]));
      }

    float inv[2][4];
    #pragma unroll
    for (int ti = 0; ti < 2; ++ti)
      #pragma unroll
      for (int h = 0; h < HEADS; ++h) {
        sc[ti][h].x = __expf(sc[ti][h].x - m[ti][h]);
        sc[ti][h].y = __expf(sc[ti][h].y - m[ti][h]);
        sc[ti][h].z = __expf(sc[ti][h].z - m[ti][h]);
        sc[ti][h].w = __expf(sc[ti][h].w - m[ti][h]);
        float s = sc[ti][h].x + sc[ti][h].y + sc[ti][h].z + sc[ti][h].w;
        for (int off = 32; off; off >>= 1) s += __shfl_xor(s, off);
        if (lane == 0) s_reds[ti * 4 + h][w] = s;
      }
    __syncthreads();
    #pragma unroll
    for (int ti = 0; ti < 2; ++ti)
      #pragma unroll
      for (int h = 0; h < HEADS; ++h) {
        const int idx = ti * 4 + h;
        inv[ti][h] = 0.25f / (s_reds[idx][0] + s_reds[idx][1] + s_reds[idx][2] + s_reds[idx][3]);
      }

    #pragma unroll
    for (int ti = 0; ti < 2; ++ti) {
      float4 o;
      o.x = sc[ti][0].x * inv[ti][0] + sc[ti][1].x * inv[ti][1] +
            sc[ti][2].x * inv[ti][2] + sc[ti][3].x * inv[ti][3];
      o.y = sc[ti][0].y * inv[ti][0] + sc[ti][1].y * inv[ti][1] +
            sc[ti][2].y * inv[ti][2] + sc[ti][3].y * inv[ti][3];
      o.z = sc[ti][0].z * inv[ti][0] + sc[ti][1].z * inv[ti][1] +
            sc[ti][2].z * inv[ti][2] + sc[ti][3].z * inv[ti][3];
      o.w = sc[ti][0].w * inv[ti][0] + sc[ti][1].w * inv[ti][1] +
            sc[ti][2].w * inv[ti][2] + sc[ti][3].w * inv[ti][3];
      ((float4*)(out0 + (size_t)(i0 + ti) * N))[t] = o;
    }
    return;
  }

  // ---------------- classifier path (512..1023) ----------------
  {
    float (*s_ac)[64] = (float(*)[64])s_buf;
    const int i0 = (b - ATTN_BLOCKS) * 2;
    if (t < 128)
      s_ac[t >> 6][t & 63] = sa_c[(i0 + (t >> 6)) * 64 + (t & 63)] + cb1[t & 63];
    __syncthreads();

    const float4* sbc4 = (const float4*)sb_cT;
    float4 ac0 = {0.f, 0.f, 0.f, 0.f}, ac1 = {0.f, 0.f, 0.f, 0.f};
    #pragma unroll 4
    for (int k = 0; k < 64; ++k) {
      const float4 sb = sbc4[k * 256 + t];
      const float a0 = s_ac[0][k], a1 = s_ac[1][k];
      const float we = cw2[k];
      ac0.x = fmaf(fmaxf(a0 + sb.x, 0.f), we, ac0.x);
      ac0.y = fmaf(fmaxf(a0 + sb.y, 0.f), we, ac0.y);
      ac0.z = fmaf(fmaxf(a0 + sb.z, 0.f), we, ac0.z);
      ac0.w = fmaf(fmaxf(a0 + sb.w, 0.f), we, ac0.w);
      ac1.x = fmaf(fmaxf(a1 + sb.x, 0.f), we, ac1.x);
      ac1.y = fmaf(fmaxf(a1 + sb.y, 0.f), we, ac1.y);
      ac1.z = fmaf(fmaxf(a1 + sb.z, 0.f), we, ac1.z);
      ac1.w = fmaf(fmaxf(a1 + sb.w, 0.f), we, ac1.w);
    }
    const float cb = cb2[0];
    float4 o0, o1;
    o0.x = 1.f / (1.f + __expf(-(ac0.x + cb)));
    o0.y = 1.f / (1.f + __expf(-(ac0.y + cb)));
    o0.z = 1.f / (1.f + __expf(-(ac0.z + cb)));
    o0.w = 1.f / (1.f + __expf(-(ac0.w + cb)));
    o1.x = 1.f / (1.f + __expf(-(ac1.x + cb)));
    o1.y = 1.f / (1.f + __expf(-(ac1.y + cb)));
    o1.z = 1.f / (1.f + __expf(-(ac1.z + cb)));
    o1.w = 1.f / (1.f + __expf(-(ac1.w + cb)));
    ((float4*)(out1 + (size_t)i0 * N))[t] = o0;
    ((float4*)(out1 + (size_t)(i0 + 1) * N))[t] = o1;
  }
}

extern "C" void kernel_launch(void* const* d_in, const int* in_sizes, int n_in,
                              void* d_out, int out_size, void* d_ws, size_t ws_size,
                              hipStream_t stream) {
  const float* nf  = (const float*)d_in[0];
  const float* ew1 = (const float*)d_in[1];
  const float* eb1 = (const float*)d_in[2];
  const float* ew2 = (const float*)d_in[3];
  const float* eb2 = (const float*)d_in[4];
  const float* ipw = (const float*)d_in[5];
  const float* ipb = (const float*)d_in[6];
  const float* pw1 = (const float*)d_in[7];
  const float* pb1 = (const float*)d_in[8];
  const float* pw2 = (const float*)d_in[9];
  const float* pb2 = (const float*)d_in[10];
  const float* cw1 = (const float*)d_in[11];
  const float* cb1 = (const float*)d_in[12];
  const float* cw2 = (const float*)d_in[13];
  const float* cb2 = (const float*)d_in[14];

  float* ws = (float*)d_ws;
  float* q     = ws + 131072;        // 1024*128
  float* kkT   = ws + 262144;        // 128*1024 (transposed)
  float* sa_pb = ws + 393216;        // 1024*128 (pb1 folded)
  float* sb_ps = ws + 524288;        // 1024*128 (MFMA-swizzled)
  float* sa_c  = ws + 655360;        // 1024*64
  float* sb_cT = ws + 720896;        // 64*1024 (transposed)
  unsigned short* w2f = (unsigned short*)(ws + 786432);  // 8*64*8 bf16

  float* out0 = (float*)d_out;             // attention_weights [1024*1024]
  float* out1 = out0 + N * N;              // edge_probabilities [1024*1024]
  float* out2 = out0 + 2 * N * N;          // predicted_edge_features [1024*1024*17]

  k_front<<<513, 256, 0, stream>>>(nf, ew1, eb1, ew2, eb2, ipw, ipb, pw1, pb1, cw1, pw2,
                                   q, kkT, sa_pb, sb_ps, sa_c, sb_cT, w2f);
  k_main<<<ATTN_BLOCKS + CLS_BLOCKS + PAIR_BLOCKS, 256, 0, stream>>>(
      sa_pb, sb_ps, w2f, pb2, q, kkT, sa_c, sb_cT, cb1, cw2, cb2, out0, out1, out2);
}